// Round 4
// baseline (741.115 us; speedup 1.0000x reference)
//
#include <hip/hip_runtime.h>

#define NF 128
#define EPS 1e-5f

typedef unsigned short ushort_t;
typedef unsigned int uint_t;

// ---------------- graph prep ----------------

__global__ void k_hist(const int* __restrict__ ei, int* __restrict__ scnt,
                       int* __restrict__ dcnt, int E) {
    int e = blockIdx.x * 256 + threadIdx.x;
    if (e < E) {
        atomicAdd(&scnt[ei[e]], 1);
        atomicAdd(&dcnt[ei[E + e]], 1);
    }
}

__global__ void k_dinv(const int* __restrict__ scnt, float* __restrict__ dinv, int n) {
    int i = blockIdx.x * 256 + threadIdx.x;
    if (i < n) dinv[i] = rsqrtf((float)scnt[i] + 1.0f);
}

// padded row length: real edges + self, rounded up to 4
static __device__ inline int padlen(int c) { return (c + 4) & ~3; }

__global__ void scan1(const int* __restrict__ dcnt, int* __restrict__ part, int n) {
    int b = blockIdx.x, t = threadIdx.x;
    int base = b * 1024 + t * 4;
    int s = 0;
#pragma unroll
    for (int k = 0; k < 4; ++k) {
        int i = base + k;
        if (i < n) s += padlen(dcnt[i]);
    }
    __shared__ int red[256];
    red[t] = s;
    __syncthreads();
    for (int off = 128; off > 0; off >>= 1) {
        if (t < off) red[t] += red[t + off];
        __syncthreads();
    }
    if (t == 0) part[b] = red[0];
}

__global__ void scan2(int* __restrict__ part, int* __restrict__ rowptr, int nb, int n) {
    __shared__ int lds[256];
    int t = threadIdx.x;
    int v = (t < nb) ? part[t] : 0;
    lds[t] = v;
    __syncthreads();
    for (int off = 1; off < 256; off <<= 1) {
        int x = (t >= off) ? lds[t - off] : 0;
        __syncthreads();
        lds[t] += x;
        __syncthreads();
    }
    if (t < nb) part[t] = lds[t] - v;  // exclusive
    if (t == nb - 1) rowptr[n] = lds[t];
}

__global__ void scan3(const int* __restrict__ dcnt, const int* __restrict__ part,
                      int* __restrict__ rowptr, int* __restrict__ cursor, int n) {
    int b = blockIdx.x, t = threadIdx.x;
    int base = b * 1024 + t * 4;
    int c[4];
    int s = 0;
#pragma unroll
    for (int k = 0; k < 4; ++k) {
        int i = base + k;
        c[k] = (i < n) ? padlen(dcnt[i]) : 0;
        s += c[k];
    }
    __shared__ int lds[256];
    lds[t] = s;
    __syncthreads();
    for (int off = 1; off < 256; off <<= 1) {
        int x = (t >= off) ? lds[t - off] : 0;
        __syncthreads();
        lds[t] += x;
        __syncthreads();
    }
    int run = part[b] + lds[t] - s;
#pragma unroll
    for (int k = 0; k < 4; ++k) {
        int i = base + k;
        if (i < n) {
            rowptr[i] = run;
            cursor[i] = run;
            run += c[k];
        }
    }
}

// write self index at end of real edges, zero-row sentinel (n) in pad slots
__global__ void k_pad(const int* __restrict__ rowptr, const int* __restrict__ dcnt,
                      int* __restrict__ colx, int n) {
    int i = blockIdx.x * 256 + threadIdx.x;
    if (i < n) {
        int p = rowptr[i] + dcnt[i];
        colx[p] = i;
        int e1 = rowptr[i + 1];
        for (int q = p + 1; q < e1; ++q) colx[q] = n;
    }
}

__global__ void k_fill_csr(const int* __restrict__ ei, int* cursor,
                           int* __restrict__ colx, int E) {
    int e = blockIdx.x * 256 + threadIdx.x;
    if (e < E) {
        int d = ei[E + e];
        int pos = atomicAdd(&cursor[d], 1);
        colx[pos] = ei[e];
    }
}

// ---------------- batch norm ----------------

__global__ void bn_stats(const float* __restrict__ h, float* __restrict__ stats, int n) {
    int j = threadIdx.x & 127;
    int half = threadIdx.x >> 7;
    float s = 0.f, q = 0.f;
    for (int r = blockIdx.x * 2 + half; r < n; r += gridDim.x * 2) {
        float v = h[r * NF + j];
        s += v;
        q += v * v;
    }
    __shared__ float ls[256], lq[256];
    ls[threadIdx.x] = s; lq[threadIdx.x] = q;
    __syncthreads();
    if (threadIdx.x < 128) {
        atomicAdd(&stats[j], ls[threadIdx.x] + ls[threadIdx.x + 128]);
        atomicAdd(&stats[NF + j], lq[threadIdx.x] + lq[threadIdx.x + 128]);
    }
}

__global__ void bn_finalize(const float* __restrict__ stats, const float* __restrict__ g,
                            const float* __restrict__ b, float* __restrict__ ac,
                            float inv_n) {
    int j = threadIdx.x;  // 128 threads
    float mean = stats[j] * inv_n;
    float var = stats[NF + j] * inv_n - mean * mean;
    float rstd = rsqrtf(var + EPS);
    float a = g[j] * rstd;
    ac[j] = a;
    ac[NF + j] = b[j] - mean * a;
}

// ---------------- GEMM: out = opt_relu( (h*a + c) @ W + opt_bias ) ----------------
// obf: write bf16(rowscale[r] * o) to outb. stats: fused column sum/sumsq atomics.

static __device__ inline ushort_t f2bf(float f) {
    uint_t u = __float_as_uint(f);
    return (ushort_t)((u + 0x7fffu + ((u >> 16) & 1u)) >> 16);
}

__launch_bounds__(256)
__global__ void gemm_bn(const float* __restrict__ Hh, const float* __restrict__ W,
                        const float* __restrict__ ac, const float* __restrict__ bias,
                        const float* __restrict__ rowscale,
                        float* __restrict__ out, ushort_t* __restrict__ outb,
                        float* __restrict__ stats, int nrows, int relu, int obf) {
    __shared__ float hs[64][133];
    const int tid = threadIdx.x;
    const int tx = tid & 15;
    const int ty = tid >> 4;
    const int rb = blockIdx.x * 64;

#pragma unroll 8
    for (int p = 0; p < 32; ++p) {
        int idx = p * 256 + tid;
        int r = idx >> 7, k = idx & 127;
        int gr = rb + r;
        float v = (gr < nrows) ? Hh[(size_t)gr * NF + k] : 0.f;
        hs[r][k] = fmaf(v, ac[k], ac[NF + k]);
    }
    __syncthreads();

    float acc[4][8];
#pragma unroll
    for (int i = 0; i < 4; ++i)
#pragma unroll
        for (int j = 0; j < 8; ++j) acc[i][j] = 0.f;

    const int c0 = tx * 4, c1 = 64 + tx * 4;
#pragma unroll 4
    for (int k = 0; k < 128; ++k) {
        const float4 b0 = *(const float4*)&W[k * NF + c0];
        const float4 b1 = *(const float4*)&W[k * NF + c1];
#pragma unroll
        for (int i = 0; i < 4; ++i) {
            float a = hs[ty * 4 + i][k];
            acc[i][0] = fmaf(a, b0.x, acc[i][0]);
            acc[i][1] = fmaf(a, b0.y, acc[i][1]);
            acc[i][2] = fmaf(a, b0.z, acc[i][2]);
            acc[i][3] = fmaf(a, b0.w, acc[i][3]);
            acc[i][4] = fmaf(a, b1.x, acc[i][4]);
            acc[i][5] = fmaf(a, b1.y, acc[i][5]);
            acc[i][6] = fmaf(a, b1.z, acc[i][6]);
            acc[i][7] = fmaf(a, b1.w, acc[i][7]);
        }
    }

    float sj[8], qj[8];
#pragma unroll
    for (int j = 0; j < 8; ++j) { sj[j] = 0.f; qj[j] = 0.f; }

#pragma unroll
    for (int i = 0; i < 4; ++i) {
        int gr = rb + ty * 4 + i;
        if (gr < nrows) {
            float o[8];
#pragma unroll
            for (int j = 0; j < 8; ++j) {
                int c = (j < 4) ? (c0 + j) : (c1 + j - 4);
                float v = acc[i][j] + (bias ? bias[c] : 0.f);
                o[j] = relu ? fmaxf(v, 0.f) : v;
            }
            if (stats) {
#pragma unroll
                for (int j = 0; j < 8; ++j) { sj[j] += o[j]; qj[j] += o[j] * o[j]; }
            }
            if (obf) {
                float rs = rowscale ? rowscale[gr] : 1.0f;
                ushort4 p0, p1;
                p0.x = f2bf(o[0] * rs); p0.y = f2bf(o[1] * rs);
                p0.z = f2bf(o[2] * rs); p0.w = f2bf(o[3] * rs);
                p1.x = f2bf(o[4] * rs); p1.y = f2bf(o[5] * rs);
                p1.z = f2bf(o[6] * rs); p1.w = f2bf(o[7] * rs);
                *(ushort4*)&outb[(size_t)gr * NF + c0] = p0;
                *(ushort4*)&outb[(size_t)gr * NF + c1] = p1;
            } else {
                *(float4*)&out[(size_t)gr * NF + c0] = make_float4(o[0], o[1], o[2], o[3]);
                *(float4*)&out[(size_t)gr * NF + c1] = make_float4(o[4], o[5], o[6], o[7]);
            }
        }
    }

    if (stats) {
        float* lds = &hs[0][0];  // reuse: 4096 floats needed, 64*133 available
        __syncthreads();         // everyone done reading hs
#pragma unroll
        for (int j = 0; j < 8; ++j) {
            int c = (j < 4) ? (c0 + j) : (c1 + j - 4);
            lds[ty * 128 + c] = sj[j];
            lds[2048 + ty * 128 + c] = qj[j];
        }
        __syncthreads();
        if (tid < 128) {
            float s = 0.f, q = 0.f;
#pragma unroll
            for (int r = 0; r < 16; ++r) {
                s += lds[r * 128 + tid];
                q += lds[2048 + r * 128 + tid];
            }
            atomicAdd(&stats[tid], s);
            atomicAdd(&stats[NF + tid], q);
        }
    }
}

// ---------------- GCN aggregation ----------------
// Bb: bf16 [n+1][128], rows pre-scaled by dinv[r]; row n is zeros (pad sentinel).
// CSR rows include self edge + pads. out = relu(dinv[d] * sum(Bb[col]) + bias).
// stats (optional): fused column sum/sumsq of the fp32 output.

#define CVT2(u, a, b) { a = __uint_as_float((u) << 16); b = __uint_as_float((u) & 0xffff0000u); }

__launch_bounds__(256)
__global__ void k_aggregate_bf(const ushort_t* __restrict__ xwb, const int* __restrict__ rowptr,
                               const int* __restrict__ colx, const float* __restrict__ dinv,
                               const float* __restrict__ bias, float* __restrict__ out,
                               float* __restrict__ stats, int n) {
    __shared__ float red[2][16][128];
    int nl = threadIdx.x >> 4;
    int node = blockIdx.x * 16 + nl;
    int lane = threadIdx.x & 15;
    bool valid = node < n;
    const uint4* __restrict__ xq = (const uint4*)xwb;
    float acc[8];
#pragma unroll
    for (int j = 0; j < 8; ++j) acc[j] = 0.f;
    int e0 = valid ? rowptr[node] : 0;
    int e1 = valid ? rowptr[node + 1] : 0;
    for (int e = e0; e < e1; e += 4) {
        int4 c4 = *(const int4*)&colx[e];
        uint4 q0 = xq[(size_t)c4.x * 16 + lane];
        uint4 q1 = xq[(size_t)c4.y * 16 + lane];
        uint4 q2 = xq[(size_t)c4.z * 16 + lane];
        uint4 q3 = xq[(size_t)c4.w * 16 + lane];
        {
            float p0, p1, p2, p3, p4, p5, p6, p7;
            CVT2(q0.x, p0, p1) CVT2(q0.y, p2, p3) CVT2(q0.z, p4, p5) CVT2(q0.w, p6, p7)
            acc[0] += p0; acc[1] += p1; acc[2] += p2; acc[3] += p3;
            acc[4] += p4; acc[5] += p5; acc[6] += p6; acc[7] += p7;
        }
        {
            float p0, p1, p2, p3, p4, p5, p6, p7;
            CVT2(q1.x, p0, p1) CVT2(q1.y, p2, p3) CVT2(q1.z, p4, p5) CVT2(q1.w, p6, p7)
            acc[0] += p0; acc[1] += p1; acc[2] += p2; acc[3] += p3;
            acc[4] += p4; acc[5] += p5; acc[6] += p6; acc[7] += p7;
        }
        {
            float p0, p1, p2, p3, p4, p5, p6, p7;
            CVT2(q2.x, p0, p1) CVT2(q2.y, p2, p3) CVT2(q2.z, p4, p5) CVT2(q2.w, p6, p7)
            acc[0] += p0; acc[1] += p1; acc[2] += p2; acc[3] += p3;
            acc[4] += p4; acc[5] += p5; acc[6] += p6; acc[7] += p7;
        }
        {
            float p0, p1, p2, p3, p4, p5, p6, p7;
            CVT2(q3.x, p0, p1) CVT2(q3.y, p2, p3) CVT2(q3.z, p4, p5) CVT2(q3.w, p6, p7)
            acc[0] += p0; acc[1] += p1; acc[2] += p2; acc[3] += p3;
            acc[4] += p4; acc[5] += p5; acc[6] += p6; acc[7] += p7;
        }
    }
    float o[8];
    if (valid) {
        float di = dinv[node];
        float4 b0 = *(const float4*)&bias[lane * 8];
        float4 b1 = *(const float4*)&bias[lane * 8 + 4];
        o[0] = fmaxf(fmaf(di, acc[0], b0.x), 0.f);
        o[1] = fmaxf(fmaf(di, acc[1], b0.y), 0.f);
        o[2] = fmaxf(fmaf(di, acc[2], b0.z), 0.f);
        o[3] = fmaxf(fmaf(di, acc[3], b0.w), 0.f);
        o[4] = fmaxf(fmaf(di, acc[4], b1.x), 0.f);
        o[5] = fmaxf(fmaf(di, acc[5], b1.y), 0.f);
        o[6] = fmaxf(fmaf(di, acc[6], b1.z), 0.f);
        o[7] = fmaxf(fmaf(di, acc[7], b1.w), 0.f);
        *(float4*)&out[(size_t)node * NF + lane * 8] = make_float4(o[0], o[1], o[2], o[3]);
        *(float4*)&out[(size_t)node * NF + lane * 8 + 4] = make_float4(o[4], o[5], o[6], o[7]);
    } else {
#pragma unroll
        for (int j = 0; j < 8; ++j) o[j] = 0.f;
    }

    if (stats) {
#pragma unroll
        for (int j = 0; j < 8; ++j) {
            red[0][nl][lane * 8 + j] = o[j];
            red[1][nl][lane * 8 + j] = o[j] * o[j];
        }
        __syncthreads();
        int tid = threadIdx.x;
        if (tid < 128) {
            float s = 0.f, q = 0.f;
#pragma unroll
            for (int r = 0; r < 16; ++r) {
                s += red[0][r][tid];
                q += red[1][r][tid];
            }
            atomicAdd(&stats[tid], s);
            atomicAdd(&stats[NF + tid], q);
        }
    }
}

// ---------------- pooling (sorted batch, stats fused) ----------------

__global__ void k_pool(const float* __restrict__ h, const int* __restrict__ batch,
                       float* __restrict__ pooled, float* __restrict__ stats, int n) {
    int g = blockIdx.x;
    int t = threadIdx.x;  // 128
    int lo = 0, hi = n;
    while (lo < hi) { int m = (lo + hi) >> 1; if (batch[m] < g) lo = m + 1; else hi = m; }
    int start = lo;
    lo = start; hi = n;
    while (lo < hi) { int m = (lo + hi) >> 1; if (batch[m] < g + 1) lo = m + 1; else hi = m; }
    int end = lo;
    float a0 = 0.f, a1 = 0.f, a2 = 0.f, a3 = 0.f;
    int r = start;
    for (; r + 4 <= end; r += 4) {
        a0 += h[(size_t)r * NF + t];
        a1 += h[(size_t)(r + 1) * NF + t];
        a2 += h[(size_t)(r + 2) * NF + t];
        a3 += h[(size_t)(r + 3) * NF + t];
    }
    for (; r < end; ++r) a0 += h[(size_t)r * NF + t];
    float val = (a0 + a1) + (a2 + a3);
    pooled[g * NF + t] = val;
    atomicAdd(&stats[t], val);
    atomicAdd(&stats[NF + t], val * val);
}

// ---------------- classifier + log_softmax ----------------

__global__ void k_cls(const float* __restrict__ h, const float* __restrict__ ac,
                      const float* __restrict__ Wc, const float* __restrict__ bc,
                      float* __restrict__ out, int C_) {
    __shared__ float hr[128];
    __shared__ float lg[16];
    __shared__ float lse_s;
    int r = blockIdx.x, t = threadIdx.x;  // 64 threads
    hr[t]      = fmaf(h[r * NF + t],      ac[t],      ac[NF + t]);
    hr[t + 64] = fmaf(h[r * NF + 64 + t], ac[64 + t], ac[NF + 64 + t]);
    __syncthreads();
    if (t < C_) {
        float s = bc[t];
        for (int k = 0; k < 128; ++k) s = fmaf(hr[k], Wc[k * C_ + t], s);
        lg[t] = s;
    }
    __syncthreads();
    if (t == 0) {
        float m = -1e30f;
        for (int c = 0; c < C_; ++c) m = fmaxf(m, lg[c]);
        float se = 0.f;
        for (int c = 0; c < C_; ++c) se += expf(lg[c] - m);
        lse_s = m + logf(se);
    }
    __syncthreads();
    if (t < C_) out[r * C_ + t] = lg[t] - lse_s;
}

// ---------------- launch ----------------

extern "C" void kernel_launch(void* const* d_in, const int* in_sizes, int n_in,
                              void* d_out, int out_size, void* d_ws, size_t ws_size,
                              hipStream_t stream) {
    const float* x          = (const float*)d_in[0];
    const int*   ei         = (const int*)d_in[1];
    const int*   batch      = (const int*)d_in[2];
    const float* bn_feat_g  = (const float*)d_in[3];
    const float* bn_feat_b  = (const float*)d_in[4];
    const float* W_feat     = (const float*)d_in[5];
    const float* bns_conv_g = (const float*)d_in[6];
    const float* bns_conv_b = (const float*)d_in[7];
    const float* W_conv     = (const float*)d_in[8];
    const float* b_conv     = (const float*)d_in[9];
    const float* bn_fc_g    = (const float*)d_in[10];
    const float* bn_fc_b    = (const float*)d_in[11];
    const float* W_lin      = (const float*)d_in[12];
    const float* b_lin      = (const float*)d_in[13];
    const float* bn_hid_g   = (const float*)d_in[14];
    const float* bn_hid_b   = (const float*)d_in[15];
    const float* W_cls      = (const float*)d_in[16];
    const float* b_cls      = (const float*)d_in[17];
    float* outp = (float*)d_out;

    const int N_ = in_sizes[2];
    const int E_ = in_sizes[1] / 2;
    const int C_ = 10;
    const int G_ = out_size / C_;
    const int Epad = E_ + 4 * N_;        // padded CSR capacity (self + pad-to-4)
    const int NB1 = (N_ + 1023) / 1024;  // scan blocks (<=256)

    char* wsp = (char*)d_ws;
    auto alloc = [&](size_t bytes) {
        void* p = (void*)wsp;
        wsp += (bytes + 255) & ~(size_t)255;
        return p;
    };
    float*    A      = (float*)alloc((size_t)N_ * NF * 4);
    ushort_t* Bb     = (ushort_t*)alloc((size_t)(N_ + 1) * NF * 2);  // +1 zero row
    float*    dinv   = (float*)alloc((size_t)N_ * 4);
    int*      cnts   = (int*)alloc((size_t)2 * N_ * 4);  // scnt | dcnt
    int*      rowptr = (int*)alloc((size_t)(N_ + 1) * 4);
    int*      cursor = (int*)alloc((size_t)(N_ + 1) * 4);
    int*      part   = (int*)alloc(256 * 4);
    int*      colx   = (int*)alloc((size_t)Epad * 4);
    float*    statsA = (float*)alloc(6 * 256 * 4);  // x, feat, a1, a2, pool, y2
    float*    ac     = (float*)alloc(256 * 4);
    float*    pooled = (float*)alloc((size_t)G_ * NF * 4);
    float*    y2     = (float*)alloc((size_t)G_ * NF * 4);

    int* scnt = cnts;
    int* dcnt = cnts + N_;
    float* st_x  = statsA;
    float* st_f  = statsA + 256;
    float* st_a1 = statsA + 512;
    float* st_a2 = statsA + 768;
    float* st_pl = statsA + 1024;
    float* st_y2 = statsA + 1280;

    int nb_n = (N_ + 255) / 256;
    int nb_e = (E_ + 255) / 256;

    // zero-init scratch that needs it
    hipMemsetAsync(cnts, 0, (size_t)2 * N_ * 4, stream);
    hipMemsetAsync(statsA, 0, 6 * 256 * 4, stream);
    hipMemsetAsync(Bb + (size_t)N_ * NF, 0, NF * 2, stream);  // sentinel row

    // graph prep
    k_hist<<<nb_e, 256, 0, stream>>>(ei, scnt, dcnt, E_);
    k_dinv<<<nb_n, 256, 0, stream>>>(scnt, dinv, N_);
    scan1<<<NB1, 256, 0, stream>>>(dcnt, part, N_);
    scan2<<<1, 256, 0, stream>>>(part, rowptr, NB1, N_);
    scan3<<<NB1, 256, 0, stream>>>(dcnt, part, rowptr, cursor, N_);
    k_pad<<<nb_n, 256, 0, stream>>>(rowptr, dcnt, colx, N_);
    k_fill_csr<<<nb_e, 256, 0, stream>>>(ei, cursor, colx, E_);

    // feat: A = relu( bn(x) @ W_feat ), stats(A) fused
    bn_stats<<<512, 256, 0, stream>>>(x, st_x, N_);
    bn_finalize<<<1, 128, 0, stream>>>(st_x, bn_feat_g, bn_feat_b, ac, 1.0f / N_);
    gemm_bn<<<(N_ + 63) / 64, 256, 0, stream>>>(x, W_feat, ac, nullptr, nullptr,
                                                A, nullptr, st_f, N_, 1, 0);

    // conv layers
    float* st_in[3] = {st_f, st_a1, st_a2};
    float* st_out[3] = {st_a1, st_a2, nullptr};
    for (int l = 0; l < 3; ++l) {
        bn_finalize<<<1, 128, 0, stream>>>(st_in[l], bns_conv_g + l * NF,
                                           bns_conv_b + l * NF, ac, 1.0f / N_);
        gemm_bn<<<(N_ + 63) / 64, 256, 0, stream>>>(A, W_conv + (size_t)l * NF * NF, ac,
                                                    nullptr, dinv, nullptr, Bb, nullptr,
                                                    N_, 0, 1);
        k_aggregate_bf<<<(N_ + 15) / 16, 256, 0, stream>>>(Bb, rowptr, colx, dinv,
                                                           b_conv + l * NF, A, st_out[l], N_);
    }

    // pool (stats fused)
    k_pool<<<G_, 128, 0, stream>>>(A, batch, pooled, st_pl, N_);

    // fc: y2 = relu( bn(pooled) @ W_lin + b_lin ), stats(y2) fused
    bn_finalize<<<1, 128, 0, stream>>>(st_pl, bn_fc_g, bn_fc_b, ac, 1.0f / G_);
    gemm_bn<<<(G_ + 63) / 64, 256, 0, stream>>>(pooled, W_lin, ac, b_lin, nullptr,
                                                y2, nullptr, st_y2, G_, 1, 0);

    // classifier
    bn_finalize<<<1, 128, 0, stream>>>(st_y2, bn_hid_g, bn_hid_b, ac, 1.0f / G_);
    k_cls<<<G_, 64, 0, stream>>>(y2, ac, W_cls, b_cls, outp, C_);
}

// Round 5
// 681.468 us; speedup vs baseline: 1.0875x; 1.0875x over previous
//
#include <hip/hip_runtime.h>

#define NF 128
#define EPS 1e-5f

typedef unsigned short ushort_t;
typedef unsigned int uint_t;

// ---------------- graph prep ----------------

__global__ void k_hist(const int* __restrict__ ei, int* __restrict__ scnt,
                       int* __restrict__ dcnt, int E) {
    int e = blockIdx.x * 256 + threadIdx.x;
    if (e < E) {
        atomicAdd(&scnt[ei[e]], 1);
        atomicAdd(&dcnt[ei[E + e]], 1);
    }
}

__global__ void k_dinv(const int* __restrict__ scnt, float* __restrict__ dinv, int n) {
    int i = blockIdx.x * 256 + threadIdx.x;
    if (i < n) dinv[i] = rsqrtf((float)scnt[i] + 1.0f);
}

// padded row length: real edges + self, rounded up to 8 (MLP=8 in gather loop)
static __device__ inline int padlen(int c) { return (c + 8) & ~7; }

__global__ void scan1(const int* __restrict__ dcnt, int* __restrict__ part, int n) {
    int b = blockIdx.x, t = threadIdx.x;
    int base = b * 1024 + t * 4;
    int s = 0;
#pragma unroll
    for (int k = 0; k < 4; ++k) {
        int i = base + k;
        if (i < n) s += padlen(dcnt[i]);
    }
    __shared__ int red[256];
    red[t] = s;
    __syncthreads();
    for (int off = 128; off > 0; off >>= 1) {
        if (t < off) red[t] += red[t + off];
        __syncthreads();
    }
    if (t == 0) part[b] = red[0];
}

__global__ void scan2(int* __restrict__ part, int* __restrict__ rowptr, int nb, int n) {
    __shared__ int lds[256];
    int t = threadIdx.x;
    int v = (t < nb) ? part[t] : 0;
    lds[t] = v;
    __syncthreads();
    for (int off = 1; off < 256; off <<= 1) {
        int x = (t >= off) ? lds[t - off] : 0;
        __syncthreads();
        lds[t] += x;
        __syncthreads();
    }
    if (t < nb) part[t] = lds[t] - v;  // exclusive
    if (t == nb - 1) rowptr[n] = lds[t];
}

__global__ void scan3(const int* __restrict__ dcnt, const int* __restrict__ part,
                      int* __restrict__ rowptr, int* __restrict__ cursor, int n) {
    int b = blockIdx.x, t = threadIdx.x;
    int base = b * 1024 + t * 4;
    int c[4];
    int s = 0;
#pragma unroll
    for (int k = 0; k < 4; ++k) {
        int i = base + k;
        c[k] = (i < n) ? padlen(dcnt[i]) : 0;
        s += c[k];
    }
    __shared__ int lds[256];
    lds[t] = s;
    __syncthreads();
    for (int off = 1; off < 256; off <<= 1) {
        int x = (t >= off) ? lds[t - off] : 0;
        __syncthreads();
        lds[t] += x;
        __syncthreads();
    }
    int run = part[b] + lds[t] - s;
#pragma unroll
    for (int k = 0; k < 4; ++k) {
        int i = base + k;
        if (i < n) {
            rowptr[i] = run;
            cursor[i] = run;
            run += c[k];
        }
    }
}

// write self index after real edges, zero-row sentinel (n) in pad slots
__global__ void k_pad(const int* __restrict__ rowptr, const int* __restrict__ dcnt,
                      int* __restrict__ colx, int n) {
    int i = blockIdx.x * 256 + threadIdx.x;
    if (i < n) {
        int p = rowptr[i] + dcnt[i];
        colx[p] = i;
        int e1 = rowptr[i + 1];
        for (int q = p + 1; q < e1; ++q) colx[q] = n;
    }
}

__global__ void k_fill_csr(const int* __restrict__ ei, int* cursor,
                           int* __restrict__ colx, int E) {
    int e = blockIdx.x * 256 + threadIdx.x;
    if (e < E) {
        int d = ei[E + e];
        int pos = atomicAdd(&cursor[d], 1);
        colx[pos] = ei[e];
    }
}

// ---------------- batch norm ----------------

__global__ void bn_stats(const float* __restrict__ h, float* __restrict__ stats, int n) {
    int j = threadIdx.x & 127;
    int half = threadIdx.x >> 7;
    float s = 0.f, q = 0.f;
    for (int r = blockIdx.x * 2 + half; r < n; r += gridDim.x * 2) {
        float v = h[r * NF + j];
        s += v;
        q += v * v;
    }
    __shared__ float ls[256], lq[256];
    ls[threadIdx.x] = s; lq[threadIdx.x] = q;
    __syncthreads();
    if (threadIdx.x < 128) {
        atomicAdd(&stats[j], ls[threadIdx.x] + ls[threadIdx.x + 128]);
        atomicAdd(&stats[NF + j], lq[threadIdx.x] + lq[threadIdx.x + 128]);
    }
}

__global__ void bn_finalize(const float* __restrict__ stats, const float* __restrict__ g,
                            const float* __restrict__ b, float* __restrict__ ac,
                            float inv_n) {
    int j = threadIdx.x;  // 128 threads
    float mean = stats[j] * inv_n;
    float var = stats[NF + j] * inv_n - mean * mean;
    float rstd = rsqrtf(var + EPS);
    float a = g[j] * rstd;
    ac[j] = a;
    ac[NF + j] = b[j] - mean * a;
}

// ---------------- GEMM: out = opt_relu( (h*a + c) @ W + opt_bias ) ----------------
// obf: write bf16(rowscale[r] * o) to outb instead of fp32 to out.

static __device__ inline ushort_t f2bf(float f) {
    uint_t u = __float_as_uint(f);
    return (ushort_t)((u + 0x7fffu + ((u >> 16) & 1u)) >> 16);
}

__launch_bounds__(256)
__global__ void gemm_bn(const float* __restrict__ Hh, const float* __restrict__ W,
                        const float* __restrict__ ac, const float* __restrict__ bias,
                        const float* __restrict__ rowscale,
                        float* __restrict__ out, ushort_t* __restrict__ outb,
                        int nrows, int relu, int obf) {
    __shared__ float hs[64][133];
    const int tid = threadIdx.x;
    const int tx = tid & 15;
    const int ty = tid >> 4;
    const int rb = blockIdx.x * 64;

#pragma unroll 8
    for (int p = 0; p < 32; ++p) {
        int idx = p * 256 + tid;
        int r = idx >> 7, k = idx & 127;
        int gr = rb + r;
        float v = (gr < nrows) ? Hh[(size_t)gr * NF + k] : 0.f;
        hs[r][k] = fmaf(v, ac[k], ac[NF + k]);
    }
    __syncthreads();

    float acc[4][8];
#pragma unroll
    for (int i = 0; i < 4; ++i)
#pragma unroll
        for (int j = 0; j < 8; ++j) acc[i][j] = 0.f;

    const int c0 = tx * 4, c1 = 64 + tx * 4;
#pragma unroll 4
    for (int k = 0; k < 128; ++k) {
        const float4 b0 = *(const float4*)&W[k * NF + c0];
        const float4 b1 = *(const float4*)&W[k * NF + c1];
#pragma unroll
        for (int i = 0; i < 4; ++i) {
            float a = hs[ty * 4 + i][k];
            acc[i][0] = fmaf(a, b0.x, acc[i][0]);
            acc[i][1] = fmaf(a, b0.y, acc[i][1]);
            acc[i][2] = fmaf(a, b0.z, acc[i][2]);
            acc[i][3] = fmaf(a, b0.w, acc[i][3]);
            acc[i][4] = fmaf(a, b1.x, acc[i][4]);
            acc[i][5] = fmaf(a, b1.y, acc[i][5]);
            acc[i][6] = fmaf(a, b1.z, acc[i][6]);
            acc[i][7] = fmaf(a, b1.w, acc[i][7]);
        }
    }

#pragma unroll
    for (int i = 0; i < 4; ++i) {
        int gr = rb + ty * 4 + i;
        if (gr < nrows) {
            float o[8];
#pragma unroll
            for (int j = 0; j < 8; ++j) {
                int c = (j < 4) ? (c0 + j) : (c1 + j - 4);
                float v = acc[i][j] + (bias ? bias[c] : 0.f);
                o[j] = relu ? fmaxf(v, 0.f) : v;
            }
            if (obf) {
                float rs = rowscale ? rowscale[gr] : 1.0f;
                ushort4 p0, p1;
                p0.x = f2bf(o[0] * rs); p0.y = f2bf(o[1] * rs);
                p0.z = f2bf(o[2] * rs); p0.w = f2bf(o[3] * rs);
                p1.x = f2bf(o[4] * rs); p1.y = f2bf(o[5] * rs);
                p1.z = f2bf(o[6] * rs); p1.w = f2bf(o[7] * rs);
                *(ushort4*)&outb[(size_t)gr * NF + c0] = p0;
                *(ushort4*)&outb[(size_t)gr * NF + c1] = p1;
            } else {
                *(float4*)&out[(size_t)gr * NF + c0] = make_float4(o[0], o[1], o[2], o[3]);
                *(float4*)&out[(size_t)gr * NF + c1] = make_float4(o[4], o[5], o[6], o[7]);
            }
        }
    }
}

// ---------------- GCN aggregation (lean: no LDS, no barrier, MLP=8) ----------------
// Bb: bf16 [n+1][128], rows pre-scaled by dinv[r]; row n = zeros (pad sentinel).
// CSR rows include self edge + pads (multiple of 8). out = relu(dinv[d]*sum + bias).

#define CVT2(u, a, b) { a = __uint_as_float((u) << 16); b = __uint_as_float((u) & 0xffff0000u); }
#define ACC8(q) { float p0, p1, p2, p3, p4, p5, p6, p7;                          \
    CVT2(q.x, p0, p1) CVT2(q.y, p2, p3) CVT2(q.z, p4, p5) CVT2(q.w, p6, p7)      \
    acc[0] += p0; acc[1] += p1; acc[2] += p2; acc[3] += p3;                      \
    acc[4] += p4; acc[5] += p5; acc[6] += p6; acc[7] += p7; }

__launch_bounds__(256)
__global__ void k_aggregate_bf(const ushort_t* __restrict__ xwb, const int* __restrict__ rowptr,
                               const int* __restrict__ colx, const float* __restrict__ dinv,
                               const float* __restrict__ bias, float* __restrict__ out, int n) {
    int node = blockIdx.x * 16 + (threadIdx.x >> 4);
    int lane = threadIdx.x & 15;
    if (node >= n) return;
    const uint4* __restrict__ xq = (const uint4*)xwb;
    float acc[8];
#pragma unroll
    for (int j = 0; j < 8; ++j) acc[j] = 0.f;
    int e0 = rowptr[node], e1 = rowptr[node + 1];
    for (int e = e0; e < e1; e += 8) {
        int4 ca = *(const int4*)&colx[e];
        int4 cb = *(const int4*)&colx[e + 4];
        uint4 q0 = xq[(size_t)ca.x * 16 + lane];
        uint4 q1 = xq[(size_t)ca.y * 16 + lane];
        uint4 q2 = xq[(size_t)ca.z * 16 + lane];
        uint4 q3 = xq[(size_t)ca.w * 16 + lane];
        uint4 q4 = xq[(size_t)cb.x * 16 + lane];
        uint4 q5 = xq[(size_t)cb.y * 16 + lane];
        uint4 q6 = xq[(size_t)cb.z * 16 + lane];
        uint4 q7 = xq[(size_t)cb.w * 16 + lane];
        ACC8(q0) ACC8(q1) ACC8(q2) ACC8(q3)
        ACC8(q4) ACC8(q5) ACC8(q6) ACC8(q7)
    }
    float di = dinv[node];
    float4 b0 = *(const float4*)&bias[lane * 8];
    float4 b1 = *(const float4*)&bias[lane * 8 + 4];
    float4 o0, o1;
    o0.x = fmaxf(fmaf(di, acc[0], b0.x), 0.f);
    o0.y = fmaxf(fmaf(di, acc[1], b0.y), 0.f);
    o0.z = fmaxf(fmaf(di, acc[2], b0.z), 0.f);
    o0.w = fmaxf(fmaf(di, acc[3], b0.w), 0.f);
    o1.x = fmaxf(fmaf(di, acc[4], b1.x), 0.f);
    o1.y = fmaxf(fmaf(di, acc[5], b1.y), 0.f);
    o1.z = fmaxf(fmaf(di, acc[6], b1.z), 0.f);
    o1.w = fmaxf(fmaf(di, acc[7], b1.w), 0.f);
    *(float4*)&out[(size_t)node * NF + lane * 8] = o0;
    *(float4*)&out[(size_t)node * NF + lane * 8 + 4] = o1;
}

// ---------------- pooling (sorted batch, stats fused) ----------------

__global__ void k_pool(const float* __restrict__ h, const int* __restrict__ batch,
                       float* __restrict__ pooled, float* __restrict__ stats, int n) {
    int g = blockIdx.x;
    int t = threadIdx.x;  // 128
    int lo = 0, hi = n;
    while (lo < hi) { int m = (lo + hi) >> 1; if (batch[m] < g) lo = m + 1; else hi = m; }
    int start = lo;
    lo = start; hi = n;
    while (lo < hi) { int m = (lo + hi) >> 1; if (batch[m] < g + 1) lo = m + 1; else hi = m; }
    int end = lo;
    float a0 = 0.f, a1 = 0.f, a2 = 0.f, a3 = 0.f;
    int r = start;
    for (; r + 4 <= end; r += 4) {
        a0 += h[(size_t)r * NF + t];
        a1 += h[(size_t)(r + 1) * NF + t];
        a2 += h[(size_t)(r + 2) * NF + t];
        a3 += h[(size_t)(r + 3) * NF + t];
    }
    for (; r < end; ++r) a0 += h[(size_t)r * NF + t];
    float val = (a0 + a1) + (a2 + a3);
    pooled[g * NF + t] = val;
    atomicAdd(&stats[t], val);
    atomicAdd(&stats[NF + t], val * val);
}

// ---------------- classifier + log_softmax ----------------

__global__ void k_cls(const float* __restrict__ h, const float* __restrict__ ac,
                      const float* __restrict__ Wc, const float* __restrict__ bc,
                      float* __restrict__ out, int C_) {
    __shared__ float hr[128];
    __shared__ float lg[16];
    __shared__ float lse_s;
    int r = blockIdx.x, t = threadIdx.x;  // 64 threads
    hr[t]      = fmaf(h[r * NF + t],      ac[t],      ac[NF + t]);
    hr[t + 64] = fmaf(h[r * NF + 64 + t], ac[64 + t], ac[NF + 64 + t]);
    __syncthreads();
    if (t < C_) {
        float s = bc[t];
        for (int k = 0; k < 128; ++k) s = fmaf(hr[k], Wc[k * C_ + t], s);
        lg[t] = s;
    }
    __syncthreads();
    if (t == 0) {
        float m = -1e30f;
        for (int c = 0; c < C_; ++c) m = fmaxf(m, lg[c]);
        float se = 0.f;
        for (int c = 0; c < C_; ++c) se += expf(lg[c] - m);
        lse_s = m + logf(se);
    }
    __syncthreads();
    if (t < C_) out[r * C_ + t] = lg[t] - lse_s;
}

// ---------------- launch ----------------

extern "C" void kernel_launch(void* const* d_in, const int* in_sizes, int n_in,
                              void* d_out, int out_size, void* d_ws, size_t ws_size,
                              hipStream_t stream) {
    const float* x          = (const float*)d_in[0];
    const int*   ei         = (const int*)d_in[1];
    const int*   batch      = (const int*)d_in[2];
    const float* bn_feat_g  = (const float*)d_in[3];
    const float* bn_feat_b  = (const float*)d_in[4];
    const float* W_feat     = (const float*)d_in[5];
    const float* bns_conv_g = (const float*)d_in[6];
    const float* bns_conv_b = (const float*)d_in[7];
    const float* W_conv     = (const float*)d_in[8];
    const float* b_conv     = (const float*)d_in[9];
    const float* bn_fc_g    = (const float*)d_in[10];
    const float* bn_fc_b    = (const float*)d_in[11];
    const float* W_lin      = (const float*)d_in[12];
    const float* b_lin      = (const float*)d_in[13];
    const float* bn_hid_g   = (const float*)d_in[14];
    const float* bn_hid_b   = (const float*)d_in[15];
    const float* W_cls      = (const float*)d_in[16];
    const float* b_cls      = (const float*)d_in[17];
    float* outp = (float*)d_out;

    const int N_ = in_sizes[2];
    const int E_ = in_sizes[1] / 2;
    const int C_ = 10;
    const int G_ = out_size / C_;
    const int Epad = E_ + 8 * N_;        // padded CSR capacity (self + pad-to-8)
    const int NB1 = (N_ + 1023) / 1024;  // scan blocks (<=256)

    char* wsp = (char*)d_ws;
    auto alloc = [&](size_t bytes) {
        void* p = (void*)wsp;
        wsp += (bytes + 255) & ~(size_t)255;
        return p;
    };
    float*    A      = (float*)alloc((size_t)N_ * NF * 4);
    ushort_t* Bb     = (ushort_t*)alloc((size_t)(N_ + 1) * NF * 2);  // +1 zero row
    float*    dinv   = (float*)alloc((size_t)N_ * 4);
    int*      cnts   = (int*)alloc((size_t)2 * N_ * 4);  // scnt | dcnt
    int*      rowptr = (int*)alloc((size_t)(N_ + 1) * 4);
    int*      cursor = (int*)alloc((size_t)(N_ + 1) * 4);
    int*      part   = (int*)alloc(256 * 4);
    int*      colx   = (int*)alloc((size_t)Epad * 4);
    float*    statsA = (float*)alloc(6 * 256 * 4);
    float*    ac     = (float*)alloc(256 * 4);
    float*    pooled = (float*)alloc((size_t)G_ * NF * 4);
    float*    y2     = (float*)alloc((size_t)G_ * NF * 4);

    int* scnt = cnts;
    int* dcnt = cnts + N_;
    float* st_x  = statsA;
    float* st_f  = statsA + 256;
    float* st_a1 = statsA + 512;
    float* st_a2 = statsA + 768;
    float* st_pl = statsA + 1024;
    float* st_y2 = statsA + 1280;

    int nb_n = (N_ + 255) / 256;
    int nb_e = (E_ + 255) / 256;

    hipMemsetAsync(cnts, 0, (size_t)2 * N_ * 4, stream);
    hipMemsetAsync(statsA, 0, 6 * 256 * 4, stream);
    hipMemsetAsync(Bb + (size_t)N_ * NF, 0, NF * 2, stream);  // sentinel row

    // graph prep
    k_hist<<<nb_e, 256, 0, stream>>>(ei, scnt, dcnt, E_);
    k_dinv<<<nb_n, 256, 0, stream>>>(scnt, dinv, N_);
    scan1<<<NB1, 256, 0, stream>>>(dcnt, part, N_);
    scan2<<<1, 256, 0, stream>>>(part, rowptr, NB1, N_);
    scan3<<<NB1, 256, 0, stream>>>(dcnt, part, rowptr, cursor, N_);
    k_pad<<<nb_n, 256, 0, stream>>>(rowptr, dcnt, colx, N_);
    k_fill_csr<<<nb_e, 256, 0, stream>>>(ei, cursor, colx, E_);

    // feat: A = relu( bn(x) @ W_feat )
    bn_stats<<<512, 256, 0, stream>>>(x, st_x, N_);
    bn_finalize<<<1, 128, 0, stream>>>(st_x, bn_feat_g, bn_feat_b, ac, 1.0f / N_);
    gemm_bn<<<(N_ + 63) / 64, 256, 0, stream>>>(x, W_feat, ac, nullptr, nullptr,
                                                A, nullptr, N_, 1, 0);
    bn_stats<<<512, 256, 0, stream>>>(A, st_f, N_);

    // conv layers
    float* st_in[3] = {st_f, st_a1, st_a2};
    float* st_out[3] = {st_a1, st_a2, nullptr};
    for (int l = 0; l < 3; ++l) {
        bn_finalize<<<1, 128, 0, stream>>>(st_in[l], bns_conv_g + l * NF,
                                           bns_conv_b + l * NF, ac, 1.0f / N_);
        gemm_bn<<<(N_ + 63) / 64, 256, 0, stream>>>(A, W_conv + (size_t)l * NF * NF, ac,
                                                    nullptr, dinv, nullptr, Bb, N_, 0, 1);
        k_aggregate_bf<<<(N_ + 15) / 16, 256, 0, stream>>>(Bb, rowptr, colx, dinv,
                                                           b_conv + l * NF, A, N_);
        if (st_out[l])
            bn_stats<<<512, 256, 0, stream>>>(A, st_out[l], N_);
    }

    // pool (stats fused)
    k_pool<<<G_, 128, 0, stream>>>(A, batch, pooled, st_pl, N_);

    // fc
    bn_finalize<<<1, 128, 0, stream>>>(st_pl, bn_fc_g, bn_fc_b, ac, 1.0f / G_);
    gemm_bn<<<(G_ + 63) / 64, 256, 0, stream>>>(pooled, W_lin, ac, b_lin, nullptr,
                                                y2, nullptr, G_, 1, 0);
    bn_stats<<<512, 256, 0, stream>>>(y2, st_y2, G_);

    // classifier
    bn_finalize<<<1, 128, 0, stream>>>(st_y2, bn_hid_g, bn_hid_b, ac, 1.0f / G_);
    k_cls<<<G_, 64, 0, stream>>>(y2, ac, W_cls, b_cls, outp, C_);
}